// Round 6
// baseline (369.152 us; speedup 1.0000x reference)
//
#include <hip/hip_runtime.h>
#include <hip/hip_bf16.h>

typedef __hip_bfloat16 bf16;
typedef __attribute__((ext_vector_type(8))) short bf16x8;   // 8 bf16 = 4 VGPRs (MFMA A/B frag)
typedef __attribute__((ext_vector_type(4))) float f32x4;    // MFMA C/D frag

#define ASYNC_CP16(gsrc, ldst)                                                              \
  __builtin_amdgcn_global_load_lds(                                                         \
      (const __attribute__((address_space(1))) unsigned int*)(gsrc),                        \
      (__attribute__((address_space(3))) unsigned int*)(ldst), 16, 0, 0)

#define BB 32
#define NN 1024
#define FF 512
#define HH 2048
#define M_ROWS (BB * NN)  // 32768

// ---------------------------------------------------------------- weight casts (fused)
__global__ __launch_bounds__(256) void cvt_pair(const float* __restrict__ a, bf16* __restrict__ da,
                                                const float* __restrict__ b, bf16* __restrict__ db,
                                                int n) {
  int i = blockIdx.x * 256 + threadIdx.x;
  if (i < n) {
    da[i] = __float2bfloat16(a[i]);
    db[i] = __float2bfloat16(b[i]);
  }
}

// ---------------------------------------------------------------- DPP xor-exchange (VALU pipe)
template <int CTRL>
__device__ __forceinline__ unsigned long long dpp_xor64(unsigned long long k) {
  int lo = (int)(unsigned)k;
  int hi = (int)(unsigned)(k >> 32);
  int plo = __builtin_amdgcn_update_dpp(lo, lo, CTRL, 0xF, 0xF, false);
  int phi = __builtin_amdgcn_update_dpp(hi, hi, CTRL, 0xF, 0xF, false);
  return (((unsigned long long)(unsigned)phi) << 32) | (unsigned)plo;
}

// ---------------------------------------------------------------- stable argsort per row
// One row of 512 per WAVE; 8 u64 keys/lane in registers.
// key = mono_u32(val) << 32 | orig_idx   (unique keys, idx tie-break => stable argsort)
// Cross-lane: DPP for d in {1,2,8} (0xB1 / 0x4E / row_ror:8), shfl_xor (bpermute) otherwise.
__global__ __launch_bounds__(256) void sort_rows_wave(const float* __restrict__ x,
                                                      unsigned* __restrict__ xs_pack,
                                                      unsigned* __restrict__ srt_pack) {
  __shared__ __align__(16) unsigned short scatx[4 * FF];
  const int t = threadIdx.x;
  const int lane = t & 63;
  const int w = t >> 6;
  const size_t row = (size_t)blockIdx.x * 4 + w;
  const float* xr = x + row * FF;

  float4 v0 = *(const float4*)(xr + lane * 8);
  float4 v1 = *(const float4*)(xr + lane * 8 + 4);
  float vals[8] = {v0.x, v0.y, v0.z, v0.w, v1.x, v1.y, v1.z, v1.w};

  unsigned long long key[8];
#pragma unroll
  for (int r = 0; r < 8; r++) {
    unsigned u = __float_as_uint(vals[r]);
    unsigned s = u ^ ((unsigned)((int)u >> 31) | 0x80000000u);  // monotone fp32->u32
    key[r] = ((unsigned long long)s << 32) | (unsigned)(lane * 8 + r);
  }

#pragma unroll
  for (int k = 2; k <= 512; k <<= 1) {
#pragma unroll
    for (int j = k >> 1; j > 0; j >>= 1) {
      if (j >= 8) {
        const int d = j >> 3;  // lane distance
#pragma unroll
        for (int r = 0; r < 8; r++) {
          unsigned long long o;
          if (d == 1)       o = dpp_xor64<0xB1>(key[r]);
          else if (d == 2)  o = dpp_xor64<0x4E>(key[r]);
          else if (d == 8)  o = dpp_xor64<0x128>(key[r]);
          else              o = __shfl_xor(key[r], d, 64);
          bool asc = (((lane * 8 + r) & k) == 0);
          bool lower = ((lane & d) == 0);
          bool keepmin = (asc == lower);
          bool minemin = key[r] < o;
          key[r] = (minemin == keepmin) ? key[r] : o;
        }
      } else {
#pragma unroll
        for (int r = 0; r < 8; r++) {
          if ((r & j) == 0) {
            const int a = r, b = r | j;
            bool asc = (((lane * 8 + a) & k) == 0);
            unsigned long long ka = key[a], kb = key[b];
            bool sw = ((ka > kb) == asc);
            key[a] = sw ? kb : ka;
            key[b] = sw ? ka : kb;
          }
        }
      }
    }
  }

  // xs scatter: sorted position v = lane*8+r holds original index j; xs[j] = bf16(vals[r]).
  const int base = w * FF;
  unsigned j8[8];
#pragma unroll
  for (int r = 0; r < 8; r++) {
    j8[r] = (unsigned)key[r] & 0xFFFFu;
    __hip_bfloat16 hb = __float2bfloat16(vals[r]);
    scatx[base + j8[r]] = *(unsigned short*)&hb;
  }

  uint4 so;
  so.x = j8[0] | (j8[1] << 16);
  so.y = j8[2] | (j8[3] << 16);
  so.z = j8[4] | (j8[5] << 16);
  so.w = j8[6] | (j8[7] << 16);
  *(uint4*)(srt_pack + row * 256 + lane * 4) = so;

  __syncthreads();
  uint4 xo = *(const uint4*)&scatx[base + lane * 8];
  *(uint4*)(xs_pack + row * 256 + lane * 4) = xo;
}

// ---------------------------------------------------------------- GEMM1 (fat block, BK=32)
// 512 threads = 8 waves (2 waveM x 4 waveN), block tile 128 x 256.
// Occupancy: 4 blocks/CU (thread-limited) -> keep LDS at 24 KB (BK=32).
template <int RELU, int K, int N>
__global__ __launch_bounds__(512, 4) void gemm_fat(const bf16* __restrict__ A,
                                                   const bf16* __restrict__ Bw,
                                                   const float* __restrict__ bias,
                                                   bf16* __restrict__ C) {
  __shared__ __align__(16) bf16 As[128 * 32];  // 8 KB
  __shared__ __align__(16) bf16 Bs[256 * 32];  // 16 KB
  const int t = threadIdx.x;
  const int lane = t & 63, wave = t >> 6;
  const int waveM = wave >> 2, waveN = wave & 3;
  const int srow = lane >> 2;
  const int scol = (lane & 3) * 8;
  const size_t mBase = (size_t)blockIdx.x * 128;
  const size_t nBase = (size_t)blockIdx.y * 256;
  const bf16* Ag  = A  + (mBase + wave * 16 + srow) * (size_t)K + scol;
  const bf16* Bg0 = Bw + (nBase + wave * 32 + srow) * (size_t)K + scol;
  const bf16* Bg1 = Bw + (nBase + wave * 32 + 16 + srow) * (size_t)K + scol;
  bf16* Al  = &As[wave * 16 * 32];
  bf16* Bl0 = &Bs[wave * 32 * 32];
  bf16* Bl1 = &Bs[(wave * 32 + 16) * 32];
  const int fr = lane & 15;
  const int fk = (lane >> 4) * 8;

  f32x4 acc[4][4];
  f32x4 zero = {0.f, 0.f, 0.f, 0.f};
#pragma unroll
  for (int i = 0; i < 4; i++)
#pragma unroll
    for (int j = 0; j < 4; j++) acc[i][j] = zero;

  for (int k0 = 0; k0 < K; k0 += 32) {
    ASYNC_CP16(Ag + k0, Al);
    ASYNC_CP16(Bg0 + k0, Bl0);
    ASYNC_CP16(Bg1 + k0, Bl1);
    __syncthreads();
    bf16x8 af[4], bfr[4];
#pragma unroll
    for (int mt = 0; mt < 4; mt++)
      af[mt] = *(const bf16x8*)&As[(waveM * 64 + mt * 16 + fr) * 32 + fk];
#pragma unroll
    for (int nt = 0; nt < 4; nt++)
      bfr[nt] = *(const bf16x8*)&Bs[(waveN * 64 + nt * 16 + fr) * 32 + fk];
#pragma unroll
    for (int mt = 0; mt < 4; mt++)
#pragma unroll
      for (int nt = 0; nt < 4; nt++)
        acc[mt][nt] = __builtin_amdgcn_mfma_f32_16x16x32_bf16(af[mt], bfr[nt], acc[mt][nt], 0, 0, 0);
    __syncthreads();
  }

  const int cn = lane & 15;
  const int cm = (lane >> 4) * 4;
  float b4[4];
#pragma unroll
  for (int nt = 0; nt < 4; nt++) b4[nt] = bias[nBase + waveN * 64 + nt * 16 + cn];
#pragma unroll
  for (int mt = 0; mt < 4; mt++) {
#pragma unroll
    for (int nt = 0; nt < 4; nt++) {
      size_t gn = nBase + waveN * 64 + nt * 16 + cn;
#pragma unroll
      for (int r = 0; r < 4; r++) {
        size_t gm = mBase + waveM * 64 + mt * 16 + cm + r;
        float v = acc[mt][nt][r] + b4[nt];
        if (RELU) v = fmaxf(v, 0.f);
        C[gm * N + gn] = __float2bfloat16(v);
      }
    }
  }
}

// ---------------------------------------------------------------- GEMM2 (fat block, BK=64)
// Grid-limited to 2 blocks/CU (512 blocks) -> LDS headroom is free: BK=64 halves the
// barrier drains (64 -> 32) and gives 32 MFMA/wave per barrier (AITER-like density).
// global_load_lds staging with 64-wide LDS rows: one 16B/lane copy = 8 rows x 64 cols,
// src mapping row=lane>>3, col=(lane&7)*8 (wave-uniform LDS base + lane*16 rule).
// Epilogue: z = A@B^T + b2 + xs (skip in sorted domain); xs may alias C (same-thread RMW).
__global__ __launch_bounds__(512, 4) void gemm2_bk64(const bf16* __restrict__ A,
                                                     const bf16* __restrict__ Bw,
                                                     const float* __restrict__ bias,
                                                     const bf16* __restrict__ xs_add,
                                                     bf16* __restrict__ C) {
  constexpr int K = HH;  // 2048
  constexpr int N = FF;  // 512
  __shared__ __align__(16) bf16 As[128 * 64];  // 16 KB
  __shared__ __align__(16) bf16 Bs[256 * 64];  // 32 KB
  const int t = threadIdx.x;
  const int lane = t & 63, wave = t >> 6;
  const int waveM = wave >> 2, waveN = wave & 3;
  const int srow = lane >> 3;          // 0..7
  const int scol = (lane & 7) * 8;     // 0..56
  const size_t mBase = (size_t)blockIdx.x * 128;
  const size_t nBase = (size_t)blockIdx.y * 256;
  // A: wave stages rows [16w,16w+16) in 2 copies of 8 rows; B: rows [32w,32w+32) in 4.
  const bf16* Ag0 = A + (mBase + wave * 16 + srow) * (size_t)K + scol;
  const bf16* Ag1 = A + (mBase + wave * 16 + 8 + srow) * (size_t)K + scol;
  const bf16* Bg0 = Bw + (nBase + wave * 32 + srow) * (size_t)K + scol;
  const bf16* Bg1 = Bw + (nBase + wave * 32 + 8 + srow) * (size_t)K + scol;
  const bf16* Bg2 = Bw + (nBase + wave * 32 + 16 + srow) * (size_t)K + scol;
  const bf16* Bg3 = Bw + (nBase + wave * 32 + 24 + srow) * (size_t)K + scol;
  bf16* Al0 = &As[(wave * 16) * 64];
  bf16* Al1 = &As[(wave * 16 + 8) * 64];
  bf16* Bl0 = &Bs[(wave * 32) * 64];
  bf16* Bl1 = &Bs[(wave * 32 + 8) * 64];
  bf16* Bl2 = &Bs[(wave * 32 + 16) * 64];
  bf16* Bl3 = &Bs[(wave * 32 + 24) * 64];
  const int fr = lane & 15;
  const int fk = (lane >> 4) * 8;

  f32x4 acc[4][4];
  f32x4 zero = {0.f, 0.f, 0.f, 0.f};
#pragma unroll
  for (int i = 0; i < 4; i++)
#pragma unroll
    for (int j = 0; j < 4; j++) acc[i][j] = zero;

  for (int k0 = 0; k0 < K; k0 += 64) {
    ASYNC_CP16(Ag0 + k0, Al0);
    ASYNC_CP16(Ag1 + k0, Al1);
    ASYNC_CP16(Bg0 + k0, Bl0);
    ASYNC_CP16(Bg1 + k0, Bl1);
    ASYNC_CP16(Bg2 + k0, Bl2);
    ASYNC_CP16(Bg3 + k0, Bl3);
    __syncthreads();
#pragma unroll
    for (int ks = 0; ks < 2; ks++) {
      bf16x8 af[4], bfr[4];
#pragma unroll
      for (int mt = 0; mt < 4; mt++)
        af[mt] = *(const bf16x8*)&As[(waveM * 64 + mt * 16 + fr) * 64 + ks * 32 + fk];
#pragma unroll
      for (int nt = 0; nt < 4; nt++)
        bfr[nt] = *(const bf16x8*)&Bs[(waveN * 64 + nt * 16 + fr) * 64 + ks * 32 + fk];
#pragma unroll
      for (int mt = 0; mt < 4; mt++)
#pragma unroll
        for (int nt = 0; nt < 4; nt++)
          acc[mt][nt] = __builtin_amdgcn_mfma_f32_16x16x32_bf16(af[mt], bfr[nt], acc[mt][nt], 0, 0, 0);
    }
    __syncthreads();
  }

  const int cn = lane & 15;
  const int cm = (lane >> 4) * 4;
  float b4[4];
#pragma unroll
  for (int nt = 0; nt < 4; nt++) b4[nt] = bias[nBase + waveN * 64 + nt * 16 + cn];
#pragma unroll
  for (int mt = 0; mt < 4; mt++) {
#pragma unroll
    for (int nt = 0; nt < 4; nt++) {
      size_t gn = nBase + waveN * 64 + nt * 16 + cn;
#pragma unroll
      for (int r = 0; r < 4; r++) {
        size_t gm = mBase + waveM * 64 + mt * 16 + cm + r;
        float v = acc[mt][nt][r] + b4[nt] + __bfloat162float(xs_add[gm * N + gn]);
        C[gm * N + gn] = __float2bfloat16(v);
      }
    }
  }
}

// ---------------------------------------------------------------- final permute (pure gather)
// out[row][i] = fp32(zp[row][srt[i]])   where zp = z + xs (summed in gemm2 epilogue)
__global__ __launch_bounds__(256) void permute_gather(const bf16* __restrict__ zp,
                                                      const unsigned* __restrict__ srt_pack,
                                                      float* __restrict__ out) {
  __shared__ __align__(16) unsigned short zr[4][FF];
  const int t = threadIdx.x;
  const int lane = t & 63;
  const int w = t >> 6;
  const size_t row = (size_t)blockIdx.x * 4 + w;

  *(uint4*)&zr[w][lane * 8] = *(const uint4*)(zp + row * FF + lane * 8);
  uint4 sv = *(const uint4*)(srt_pack + row * 256 + lane * 4);
  __syncthreads();

  unsigned idx[8] = {sv.x & 0xFFFFu, sv.x >> 16, sv.y & 0xFFFFu, sv.y >> 16,
                     sv.z & 0xFFFFu, sv.z >> 16, sv.w & 0xFFFFu, sv.w >> 16};
  float4 o0, o1;
#pragma unroll
  for (int r = 0; r < 8; r++) {
    float zf = __uint_as_float(((unsigned)zr[w][idx[r]]) << 16);
    ((r < 4) ? (&o0.x) : (&o1.x))[r & 3] = zf;
  }
  *(float4*)(out + row * FF + lane * 8) = o0;
  *(float4*)(out + row * FF + lane * 8 + 4) = o1;
}

// ---------------------------------------------------------------- launch
extern "C" void kernel_launch(void* const* d_in, const int* in_sizes, int n_in,
                              void* d_out, int out_size, void* d_ws, size_t ws_size,
                              hipStream_t stream) {
  const float* x  = (const float*)d_in[0];
  const float* W1 = (const float*)d_in[1];
  const float* b1 = (const float*)d_in[2];
  const float* W2 = (const float*)d_in[3];
  const float* b2 = (const float*)d_in[4];
  float* out = (float*)d_out;

  char* ws = (char*)d_ws;
  // z aliases xs ([M][512] bf16, identical layout): gemm2 reads xs(gm,gn) then writes
  // z(gm,gn) from the SAME thread, tiles disjoint across blocks -> safe. 196 MiB total.
  unsigned* xs  = (unsigned*)(ws);                           // 32 MiB bf16 xs
  bf16*     xsb = (bf16*)(ws);
  bf16*     z   = (bf16*)(ws);                               // aliases xs
  unsigned* srt = (unsigned*)(ws + 33554432);                // 32 MiB u16 srt
  bf16* h   = (bf16*)(ws + 67108864);                        // 128 MiB
  bf16* W1b = (bf16*)(ws + 201326592);                       // 2 MiB
  bf16* W2b = (bf16*)(ws + 203423744);                       // 2 MiB

  cvt_pair<<<(HH * FF + 255) / 256, 256, 0, stream>>>(W1, W1b, W2, W2b, HH * FF);
  sort_rows_wave<<<M_ROWS / 4, 256, 0, stream>>>(x, xs, srt);
  // h = relu(xs @ W1^T + b1): M=32768, K=512, N=2048
  gemm_fat<1, FF, HH><<<dim3(M_ROWS / 128, HH / 256), 512, 0, stream>>>(xsb, W1b, b1, h);
  // z = h @ W2^T + b2 + xs: M=32768, K=2048, N=512  (skip fused, sorted domain; BK=64)
  gemm2_bk64<<<dim3(M_ROWS / 128, FF / 256), 512, 0, stream>>>(h, W2b, b2, xsb, z);
  permute_gather<<<M_ROWS / 4, 256, 0, stream>>>(z, srt, out);
}